// Round 1
// baseline (994.246 us; speedup 1.0000x reference)
//
#include <hip/hip_runtime.h>
#include <stdint.h>

typedef __attribute__((ext_vector_type(8))) short    bh8;   // 8 x bf16 (4 VGPR)
typedef __attribute__((ext_vector_type(4))) float    fx4;   // MFMA acc
typedef __attribute__((ext_vector_type(4))) float    f4v;
typedef unsigned short u16;
typedef __attribute__((ext_vector_type(4))) unsigned short u16x4;

#define DEV static __device__ __forceinline__

DEV u16 f2bf(float f) {                       // RNE fp32 -> bf16
  unsigned u = __float_as_uint(f);
  u += 0x7FFFu + ((u >> 16) & 1u);
  return (u16)(u >> 16);
}
DEV float bf2f(u16 s) { return __uint_as_float(((unsigned)s) << 16); }
DEV float softplus_f(float x) { return fmaxf(x, 0.f) + log1pf(expf(-fabsf(x))); }

DEV void gload_lds16(const u16* g, u16* l) {  // 16B/lane async global->LDS
  __builtin_amdgcn_global_load_lds(
      (const __attribute__((address_space(1))) unsigned int*)g,
      (__attribute__((address_space(3))) unsigned int*)l, 16, 0, 0);
}

// ---------------- fp32 -> bf16 convert (vectorized) ----------------
__global__ __launch_bounds__(256) void k_cvt(const float* __restrict__ in,
                                             u16* __restrict__ out, int n4) {
  int i = blockIdx.x * 256 + threadIdx.x;
  int stride = gridDim.x * 256;
  for (; i < n4; i += stride) {
    f4v v = ((const f4v*)in)[i];
    u16x4 o;
    o.x = f2bf(v.x); o.y = f2bf(v.y); o.z = f2bf(v.z); o.w = f2bf(v.w);
    ((u16x4*)out)[i] = o;
  }
}

// ---------------- main projection GEMM: C[i,j] = sum_k A[i,k]*B[j,k] -------
// m97 structure: 128x128 tile, BK=32, 4 waves (2x2), 16x16x32 bf16 MFMA,
// global_load_lds width=16 staging, 2 barriers per K-step.
// EPI: 0 = plain, 1 = softplus, 2 = softplus + zero where mask[row]!=0
template <int EPI>
__global__ __launch_bounds__(256, 3) void k_gemm_bt(
    const u16* __restrict__ A, const u16* __restrict__ B, u16* __restrict__ C,
    const int* __restrict__ mask, int M, int N, int K) {
  __shared__ u16 lsA[128 * 32];
  __shared__ u16 lsB[128 * 32];
  int tid = threadIdx.x, lane = tid & 63, wid = tid >> 6;
  int nbn = N >> 7;
  int bm0 = (blockIdx.x / nbn) << 7;
  int bn0 = (blockIdx.x % nbn) << 7;

  // staging: wave w fills 1KB chunks {w, w+4} of each tile; chunk c = rows [16c,16c+16)
  int rA0 = wid * 16 + (lane >> 2), rA1 = (wid + 4) * 16 + (lane >> 2);
  int kk8 = (lane & 3) * 8;
  const u16* gA0 = A + (size_t)(bm0 + rA0) * K + kk8;
  const u16* gA1 = A + (size_t)(bm0 + rA1) * K + kk8;
  const u16* gB0 = B + (size_t)(bn0 + rA0) * K + kk8;
  const u16* gB1 = B + (size_t)(bn0 + rA1) * K + kk8;
  u16* lA0 = &lsA[wid * 512];
  u16* lA1 = &lsA[(wid + 4) * 512];
  u16* lB0 = &lsB[wid * 512];
  u16* lB1 = &lsB[(wid + 4) * 512];

  int wr = wid >> 1, wc = wid & 1;
  int r = lane & 15, ko = (lane >> 4) * 8;
  const u16* pa = &lsA[(wr * 64 + r) * 32 + ko];
  const u16* pb = &lsB[(wc * 64 + r) * 32 + ko];

  fx4 acc[4][4] = {};
  for (int k0 = 0; k0 < K; k0 += 32) {
    __syncthreads();
    gload_lds16(gA0 + k0, lA0);
    gload_lds16(gA1 + k0, lA1);
    gload_lds16(gB0 + k0, lB0);
    gload_lds16(gB1 + k0, lB1);
    __syncthreads();   // compiler drains vmcnt before s_barrier
    bh8 af[4], bfr[4];
#pragma unroll
    for (int mi = 0; mi < 4; mi++) af[mi] = *(const bh8*)(pa + mi * 512);
#pragma unroll
    for (int ni = 0; ni < 4; ni++) bfr[ni] = *(const bh8*)(pb + ni * 512);
#pragma unroll
    for (int mi = 0; mi < 4; mi++)
#pragma unroll
      for (int ni = 0; ni < 4; ni++)
        acc[mi][ni] = __builtin_amdgcn_mfma_f32_16x16x32_bf16(af[mi], bfr[ni],
                                                              acc[mi][ni], 0, 0, 0);
  }
  // epilogue: D row = (lane>>4)*4+reg, col = lane&15  (m89-verified)
#pragma unroll
  for (int mi = 0; mi < 4; mi++) {
#pragma unroll
    for (int ni = 0; ni < 4; ni++) {
      int gib = bm0 + wr * 64 + mi * 16 + (lane >> 4) * 4;
      int gj = bn0 + wc * 64 + ni * 16 + (lane & 15);
#pragma unroll
      for (int j = 0; j < 4; j++) {
        int gi = gib + j;
        float v = acc[mi][ni][j];
        if (EPI >= 1) v = softplus_f(v);
        if (EPI == 2) {
          if (mask[gi]) v = 0.f;
        }
        C[(size_t)gi * N + gj] = f2bf(v);
      }
    }
  }
}

// ---------------- s[n,h,d] = sum_k pk[n,k,h*128+d] ----------------
__global__ __launch_bounds__(512) void k_ssum(const u16* __restrict__ pk,
                                              float* __restrict__ s) {
  int nh = blockIdx.x;            // n*16+h
  int n = nh >> 4, h = nh & 15;
  __shared__ float red[32][128];
  int t = threadIdx.x;
  int d8 = (t & 15) * 8;          // 8 cols per thread
  int p = t >> 4;                 // 32 k-parts
  const u16* base = pk + (size_t)(n * 4096) * 2048 + h * 128 + d8;
  float a[8] = {};
  for (int k = p * 128; k < p * 128 + 128; k++) {
    bh8 v = *(const bh8*)(base + (size_t)k * 2048);
#pragma unroll
    for (int i = 0; i < 8; i++) a[i] += bf2f((u16)v[i]);
  }
#pragma unroll
  for (int i = 0; i < 8; i++) red[p][d8 + i] = a[i];
  __syncthreads();
  if (t < 128) {
    float sum = 0.f;
#pragma unroll
    for (int pp = 0; pp < 32; pp++) sum += red[pp][t];
    s[nh * 128 + t] = sum;
  }
}

// ---------------- kvT[n,h,e,d] = sum_k pk[k,d]*v[k,e] ----------------
// one block per (n,h); transposed LDS staging so both operands are
// row-with-contiguous-k for MFMA.
__global__ __launch_bounds__(256, 1) void k_kv(const u16* __restrict__ pk,
                                               const u16* __restrict__ v,
                                               u16* __restrict__ kvT) {
  int nh = blockIdx.x;
  int n = nh >> 4, h = nh & 15;
  __shared__ u16 lsA[128 * 32];   // pk^T tile: [d][k]
  __shared__ u16 lsB[128 * 32];   // v^T tile:  [e][k]
  int tid = threadIdx.x, lane = tid & 63, wid = tid >> 6;
  int wr = wid >> 1, wc = wid & 1;
  int kk = tid >> 3;              // 0..31 (k within slab)
  int dg = (tid & 7) * 16;        // 0..112 (16 cols per thread)
  size_t rowbase = ((size_t)(n * 4096) + kk) * 2048 + h * 128 + dg;
  int r = lane & 15, ko = (lane >> 4) * 8;
  fx4 acc[4][4] = {};
  for (int k0 = 0; k0 < 4096; k0 += 32) {
    __syncthreads();
    bh8 a0 = *(const bh8*)(pk + rowbase + (size_t)k0 * 2048);
    bh8 a1 = *(const bh8*)(pk + rowbase + (size_t)k0 * 2048 + 8);
    bh8 b0 = *(const bh8*)(v + rowbase + (size_t)k0 * 2048);
    bh8 b1 = *(const bh8*)(v + rowbase + (size_t)k0 * 2048 + 8);
#pragma unroll
    for (int i = 0; i < 8; i++) {
      lsA[(dg + i) * 32 + kk] = (u16)a0[i];
      lsA[(dg + 8 + i) * 32 + kk] = (u16)a1[i];
      lsB[(dg + i) * 32 + kk] = (u16)b0[i];
      lsB[(dg + 8 + i) * 32 + kk] = (u16)b1[i];
    }
    __syncthreads();
    bh8 af[4], bfr[4];
#pragma unroll
    for (int mi = 0; mi < 4; mi++)
      af[mi] = *(const bh8*)&lsA[(wr * 64 + mi * 16 + r) * 32 + ko];
#pragma unroll
    for (int ni = 0; ni < 4; ni++)
      bfr[ni] = *(const bh8*)&lsB[(wc * 64 + ni * 16 + r) * 32 + ko];
#pragma unroll
    for (int mi = 0; mi < 4; mi++)
#pragma unroll
      for (int ni = 0; ni < 4; ni++)
        acc[mi][ni] = __builtin_amdgcn_mfma_f32_16x16x32_bf16(af[mi], bfr[ni],
                                                              acc[mi][ni], 0, 0, 0);
  }
  // D rows = d, cols = e; store transposed as kvT[e][d]
#pragma unroll
  for (int mi = 0; mi < 4; mi++)
#pragma unroll
    for (int ni = 0; ni < 4; ni++)
#pragma unroll
      for (int j = 0; j < 4; j++) {
        int d = wr * 64 + mi * 16 + (lane >> 4) * 4 + j;
        int e = wc * 64 + ni * 16 + (lane & 15);
        kvT[((size_t)nh * 128 + e) * 128 + d] = f2bf(acc[mi][ni][j]);
      }
}

// ---------------- final: out = (pq @ kv) / (pq @ s), query-masked ----------
// block = (n, h, l-tile of 128). XOR-swizzled LDS (T2) since row stride=256B.
__global__ __launch_bounds__(256, 2) void k_att(
    const u16* __restrict__ pq, const u16* __restrict__ kvT,
    const float* __restrict__ s, const int* __restrict__ qmask,
    float* __restrict__ out) {
  int b = blockIdx.x;
  int lt = b & 31, h = (b >> 5) & 15, nb = b >> 9;
  int l0 = lt * 128;
  __shared__ u16 lsQ[128 * 128];
  __shared__ u16 lsKV[128 * 128];
  __shared__ float lsS[128];
  __shared__ float lsDen[128];
  int tid = threadIdx.x, lane = tid & 63, wid = tid >> 6;

  // stage pq tile (rows l) and kvT head (rows e), 16B chunks, swizzled
  int row = tid >> 1, part = tid & 1;
  const u16* gq = pq + ((size_t)(nb * 4096 + l0 + row)) * 2048 + h * 128 + part * 64;
  const u16* gk = kvT + ((size_t)(nb * 16 + h) * 128 + row) * 128 + part * 64;
  int sw = (row & 7) << 3;   // XOR on short-index bits 3..5 (16B units)
#pragma unroll
  for (int j = 0; j < 8; j++) {
    bh8 vq = *(const bh8*)(gq + j * 8);
    bh8 vk = *(const bh8*)(gk + j * 8);
    int ci = (part * 64 + j * 8) ^ sw;
    *(bh8*)&lsQ[row * 128 + ci] = vq;
    *(bh8*)&lsKV[row * 128 + ci] = vk;
  }
  if (tid < 128) lsS[tid] = s[(nb * 16 + h) * 128 + tid];
  __syncthreads();

  // den per row (rotated start to spread banks)
  if (tid < 128) {
    int rr = tid, swr = (rr & 7) << 3;
    float dsum = 0.f;
    for (int dd = 0; dd < 128; dd++) {
      int d = (dd + rr) & 127;
      dsum += bf2f(lsQ[rr * 128 + (d ^ swr)]) * lsS[d];
    }
    lsDen[rr] = dsum;
  }
  __syncthreads();

  int wr = wid >> 1, wc = wid & 1;
  int r = lane & 15, ko = (lane >> 4) * 8;
  fx4 acc[4][4] = {};
#pragma unroll
  for (int ks = 0; ks < 4; ks++) {
    bh8 af[4], bfr[4];
#pragma unroll
    for (int mi = 0; mi < 4; mi++) {
      int rw = wr * 64 + mi * 16 + r;
      af[mi] = *(const bh8*)&lsQ[rw * 128 + ((ks * 32 + ko) ^ ((rw & 7) << 3))];
    }
#pragma unroll
    for (int ni = 0; ni < 4; ni++) {
      int rw = wc * 64 + ni * 16 + r;
      bfr[ni] = *(const bh8*)&lsKV[rw * 128 + ((ks * 32 + ko) ^ ((rw & 7) << 3))];
    }
#pragma unroll
    for (int mi = 0; mi < 4; mi++)
#pragma unroll
      for (int ni = 0; ni < 4; ni++)
        acc[mi][ni] = __builtin_amdgcn_mfma_f32_16x16x32_bf16(af[mi], bfr[ni],
                                                              acc[mi][ni], 0, 0, 0);
  }
  // epilogue: divide by den, query mask, write fp32
#pragma unroll
  for (int mi = 0; mi < 4; mi++)
#pragma unroll
    for (int ni = 0; ni < 4; ni++)
#pragma unroll
      for (int j = 0; j < 4; j++) {
        int li = wr * 64 + mi * 16 + (lane >> 4) * 4 + j;   // row in tile
        int e = wc * 64 + ni * 16 + (lane & 15);
        int l = l0 + li;
        float v = qmask[nb * 4096 + l] ? 0.f : acc[mi][ni][j] / lsDen[li];
        out[((size_t)(nb * 4096 + l)) * 2048 + h * 128 + e] = v;
      }
}

// ---------------- launch ----------------
extern "C" void kernel_launch(void* const* d_in, const int* in_sizes, int n_in,
                              void* d_out, int out_size, void* d_ws, size_t ws_size,
                              hipStream_t stream) {
  const float* query = (const float*)d_in[0];
  const float* key   = (const float*)d_in[1];
  const float* Wq    = (const float*)d_in[2];
  const float* Wk    = (const float*)d_in[3];
  const float* Wv    = (const float*)d_in[4];
  const int* qmask   = (const int*)d_in[5];
  const int* kmask   = (const int*)d_in[6];
  float* out = (float*)d_out;
  char* ws = (char*)d_ws;

  // ws layout (bytes): qb 0 | kb 64M | Wqb/Wkb/Wvb | pq | kvT | s   (~218 MiB)
  u16* qb   = (u16*)(ws + 0);
  u16* kb   = (u16*)(ws + 67108864ull);
  u16* Wqb  = (u16*)(ws + 134217728ull);
  u16* Wkb  = (u16*)(ws + 142606336ull);
  u16* Wvb  = (u16*)(ws + 150994944ull);
  u16* pq   = (u16*)(ws + 159383552ull);
  u16* kvT  = (u16*)(ws + 226492416ull);
  float* sb = (float*)(ws + 228589568ull);
  // pk and v are dead before k_att -> live in d_out (2 x 67MB = exactly out bytes)
  u16* pk = (u16*)d_out;
  u16* vb = (u16*)d_out + 33554432ull;

  k_cvt<<<2048, 256, 0, stream>>>(query, qb, 33554432 / 4);
  k_cvt<<<2048, 256, 0, stream>>>(key, kb, 33554432 / 4);
  k_cvt<<<512, 256, 0, stream>>>(Wq, Wqb, 4194304 / 4);
  k_cvt<<<512, 256, 0, stream>>>(Wk, Wkb, 4194304 / 4);
  k_cvt<<<512, 256, 0, stream>>>(Wv, Wvb, 4194304 / 4);

  k_gemm_bt<1><<<2048, 256, 0, stream>>>(qb, Wqb, pq, nullptr, 16384, 2048, 2048);
  k_gemm_bt<2><<<2048, 256, 0, stream>>>(kb, Wkb, pk, kmask, 16384, 2048, 2048);
  k_gemm_bt<0><<<2048, 256, 0, stream>>>(kb, Wvb, vb, nullptr, 16384, 2048, 2048);

  k_ssum<<<64, 512, 0, stream>>>(pk, sb);
  k_kv<<<64, 256, 0, stream>>>(pk, vb, kvT);
  k_att<<<2048, 256, 0, stream>>>(pq, kvT, sb, qmask, out);
}